// Round 10
// baseline (93.807 us; speedup 1.0000x reference)
//
#include <hip/hip_runtime.h>
#include <math.h>

// PLIF (parametric LIF) forward, heterogeneous per-feature decay/threshold.
// x: [B=4, N=1024, T=128, D=128] fp32, sequential scan over T per (b,n,d):
//   v = v * sigmoid(decay[d]) + x[t]
//   s = (v > sigmoid(v_th[d]) + 0.1) ? 1 : 0
//   v = s ? 0 : v        (hard reset; exact since s in {0,1})
//
// R10: R9 (93.2us; LDS-staged wide I/O + lgkm-only barriers) with the vmem
//      ISSUE ORDER fixed. R9 issued [store,store,load,load] per chunk, so
//      the compiler's auto-wait before the staged ds_write was vmcnt(0) --
//      still gang-draining the previous chunk's NT stores every chunk (vmcnt
//      retires in issue order; the loads were youngest). Here chunk c+1's
//      loads are issued BEFORE compute(c) and written to LDS AFTER the store
//      phase: outstanding order [load,load,store,store] -> auto-wait is
//      vmcnt(2) -- loads retired, stores stay in flight across the barrier
//      (T4 counted-vmcnt + T14 issue-early/write-late). Loads also get the
//      whole compute phase to land instead of being waited immediately.
//      Same 2 lgkm-only barriers/chunk, 16KB LDS, 32 waves/CU as R9.
//
// __fmul_rn/__fadd_rn prevent fma contraction so fp32 rounding matches the
// mul-then-add numpy reference exactly (spike compares are boundary-
// sensitive: one ulp flip -> absmax 1.0). R1/R3-R9 passed absmax 0.0.

#define T_STEPS 128
#define D_FEAT  128
#define CT      8                 // time-steps per staged chunk
#define CTD     (CT * D_FEAT)     // 1024 floats per row-chunk
#define NCHUNK  (T_STEPS / CT)    // 16 chunks

typedef float f32x4 __attribute__((ext_vector_type(4)));

// Workgroup barrier WITHOUT a vmcnt drain: orders LDS ops only, leaves
// global (NT load/store) traffic in flight. sched_barrier(0) pins code
// motion (guide rule #18).
__device__ __forceinline__ void barrier_lds_only()
{
    __builtin_amdgcn_sched_barrier(0);
    asm volatile("s_waitcnt lgkmcnt(0)" ::: "memory");
    __builtin_amdgcn_s_barrier();
    __builtin_amdgcn_sched_barrier(0);
}

__global__ __launch_bounds__(256)
void plif_fwd_kernel(const f32x4* __restrict__ x4,
                     const float* __restrict__ decay,
                     const float* __restrict__ vth,
                     f32x4* __restrict__ out4)
{
    __shared__ float xs[2 * CTD];   // 8 KB: [2 rows][CT][D]
    __shared__ float ss[2 * CTD];   // 8 KB spikes

    const int tid  = threadIdx.x;
    const int lrow = tid >> 7;              // 0/1: which of the block's rows
    const int d    = tid & (D_FEAT - 1);    // feature index
    const int r0   = blockIdx.x * 2;        // first row of this block

    // per-feature constants (2 expf per thread -- negligible)
    const float dec = 1.0f / (1.0f + expf(-decay[d]));
    const float th  = 1.0f / (1.0f + expf(-vth[d])) + 0.1f;

    const size_t rowq = (size_t)T_STEPS * D_FEAT / 4;   // float4s per row
    const f32x4* __restrict__ xrA = x4 + (size_t)(r0 + 0) * rowq + (size_t)tid;
    const f32x4* __restrict__ xrB = x4 + (size_t)(r0 + 1) * rowq + (size_t)tid;
    f32x4* __restrict__ owA = out4 + (size_t)(r0 + 0) * rowq + (size_t)tid;
    f32x4* __restrict__ owB = out4 + (size_t)(r0 + 1) * rowq + (size_t)tid;

    float v = 0.0f;

    // ---- prologue: stage chunk 0 (only loads outstanding -> clean wait) ----
    f32x4 pA = __builtin_nontemporal_load(xrA);
    f32x4 pB = __builtin_nontemporal_load(xrB);
    *(f32x4*)&xs[0 * CTD + tid * 4] = pA;
    *(f32x4*)&xs[1 * CTD + tid * 4] = pB;
    barrier_lds_only();                     // xs ready for chunk 0

    for (int c = 0; c < NCHUNK; ++c) {
        const size_t cq = (size_t)c * (CTD / 4);

        // ---- issue chunk c+1 loads FIRST (oldest vmem entries) ----
        if (c + 1 < NCHUNK) {
            pA = __builtin_nontemporal_load(xrA + cq + (CTD / 4));
            pB = __builtin_nontemporal_load(xrB + cq + (CTD / 4));
        }

        // ---- compute CT steps of this thread's (row, d) chain ----
#pragma unroll
        for (int i = 0; i < CT; ++i) {
            const float xv = xs[lrow * CTD + i * D_FEAT + d];
            v = __fadd_rn(__fmul_rn(v, dec), xv);
            const bool f = (v > th);
            ss[lrow * CTD + i * D_FEAT + d] = f ? 1.0f : 0.0f;
            v = f ? 0.0f : v;
        }
        barrier_lds_only();   // ss ready AND all compute reads of xs drained

        // ---- store spikes (issued after the prefetch loads) ----
        const f32x4 s0 = *(const f32x4*)&ss[0 * CTD + tid * 4];
        const f32x4 s1 = *(const f32x4*)&ss[1 * CTD + tid * 4];
        __builtin_nontemporal_store(s0, owA + cq);
        __builtin_nontemporal_store(s1, owB + cq);

        // ---- write prefetched regs to xs: auto-wait is vmcnt(2) (loads
        //      are the oldest outstanding vmem; stores keep flying) ----
        if (c + 1 < NCHUNK) {
            __builtin_amdgcn_sched_barrier(0);  // keep store-issue above
            *(f32x4*)&xs[0 * CTD + tid * 4] = pA;
            *(f32x4*)&xs[1 * CTD + tid * 4] = pB;
            barrier_lds_only();                 // xs ready for chunk c+1
        }
    }
}

extern "C" void kernel_launch(void* const* d_in, const int* in_sizes, int n_in,
                              void* d_out, int out_size, void* d_ws, size_t ws_size,
                              hipStream_t stream)
{
    const float* x     = (const float*)d_in[0];
    const float* decay = (const float*)d_in[1];
    const float* vth   = (const float*)d_in[2];
    float*       out   = (float*)d_out;

    const int total  = in_sizes[0];                    // B*N*T*D = 67108864
    const int rows   = total / (T_STEPS * D_FEAT);     // B*N = 4096
    const int blocks = rows / 2;                       // 2048
    const int block  = 256;

    plif_fwd_kernel<<<blocks, block, 0, stream>>>(
        (const f32x4*)x, decay, vth, (f32x4*)out);
}

// Round 11
// 92.530 us; speedup vs baseline: 1.0138x; 1.0138x over previous
//
#include <hip/hip_runtime.h>
#include <math.h>

// PLIF (parametric LIF) forward, heterogeneous per-feature decay/threshold.
// x: [B=4, N=1024, T=128, D=128] fp32, sequential scan over T per (b,n,d):
//   v = v * sigmoid(decay[d]) + x[t]
//   s = (v > sigmoid(v_th[d]) + 0.1) ? 1 : 0
//   v = s ? 0 : v        (hard reset; exact since s in {0,1})
//
// FINAL (revert to R9, measured best 93.2us = 5.76 TB/s = 91.6% of the
// 6.29 TB/s measured copy ceiling; remaining gap accounted by launch/ramp
// for a 2048-block grid + LDS round-trip + barrier overhead):
//   - LDS-staged wide I/O (R6 lever, +8%): 256-thread block owns 2 rows;
//     per 8-step chunk, stage x via fully-contiguous float4 loads (1024B
//     per wave-instruction, copy-bench pattern), compute scalar chains from
//     LDS (stride-4B = 2-way bank aliasing = free), store spikes as
//     contiguous float4. 16KB LDS x 8 blocks/CU -> full 32 waves/CU.
//   - lgkm-only barriers (R9 lever, +1.2%): __syncthreads would emit
//     s_waitcnt vmcnt(0) before s_barrier, gang-stalling on NT-store
//     retirement; cross-thread exchange is purely through LDS, so
//     lgkmcnt(0)+s_barrier suffices (rule #18 sched_barrier pins motion).
//   - nontemporal load/store: 512MB streamed once, don't pollute L3.
// A/B'd and rejected: manual reg double-buffer (R4 neutral), scalar
// max-occupancy (R5 +1.6% only), CT=16 in-place (R7 -3%), barrier-free
// wave-private staging (R8 -20%), counted-vmcnt issue-reorder (R10 neutral).
//
// __fmul_rn/__fadd_rn prevent fma contraction so fp32 rounding matches the
// mul-then-add numpy reference exactly (spike compares are boundary-
// sensitive: one ulp flip -> absmax 1.0). Passed absmax 0.0 on all rounds.

#define T_STEPS 128
#define D_FEAT  128
#define CT      8                 // time-steps per staged chunk
#define CTD     (CT * D_FEAT)     // 1024 floats per row-chunk
#define NCHUNK  (T_STEPS / CT)    // 16 chunks

typedef float f32x4 __attribute__((ext_vector_type(4)));

// Workgroup barrier WITHOUT the vmcnt(0) drain __syncthreads would emit:
// orders LDS ops only, leaves global (NT store) traffic in flight.
__device__ __forceinline__ void barrier_lds_only()
{
    __builtin_amdgcn_sched_barrier(0);
    asm volatile("s_waitcnt lgkmcnt(0)" ::: "memory");
    __builtin_amdgcn_s_barrier();
    __builtin_amdgcn_sched_barrier(0);
}

__global__ __launch_bounds__(256)
void plif_fwd_kernel(const f32x4* __restrict__ x4,
                     const float* __restrict__ decay,
                     const float* __restrict__ vth,
                     f32x4* __restrict__ out4)
{
    __shared__ float xs[2 * CTD];   // 8 KB: [2 rows][CT][D]
    __shared__ float ss[2 * CTD];   // 8 KB spikes

    const int tid  = threadIdx.x;
    const int lrow = tid >> 7;              // 0/1: which of the block's rows
    const int d    = tid & (D_FEAT - 1);    // feature index
    const int r0   = blockIdx.x * 2;        // first row of this block

    // per-feature constants (2 expf per thread -- negligible)
    const float dec = 1.0f / (1.0f + expf(-decay[d]));
    const float th  = 1.0f / (1.0f + expf(-vth[d])) + 0.1f;

    const size_t rowq = (size_t)T_STEPS * D_FEAT / 4;   // float4s per row

    float v = 0.0f;

    for (int c = 0; c < NCHUNK; ++c) {
        const size_t cq = (size_t)(c * CT) * D_FEAT / 4; // chunk offset (float4)

        // ---- stage x: 2 rounds of fully-contiguous 4KB float4 loads ----
#pragma unroll
        for (int p = 0; p < 2; ++p) {
            const f32x4 tmp = __builtin_nontemporal_load(
                x4 + (size_t)(r0 + p) * rowq + cq + (size_t)tid);
            *(f32x4*)&xs[p * CTD + tid * 4] = tmp;
        }
        barrier_lds_only();   // xs visible; prior chunk's stores stay in flight

        // ---- compute CT steps of this thread's (row, d) chain ----
#pragma unroll
        for (int i = 0; i < CT; ++i) {
            const float xv = xs[lrow * CTD + i * D_FEAT + d];
            v = __fadd_rn(__fmul_rn(v, dec), xv);
            const bool f = (v > th);
            ss[lrow * CTD + i * D_FEAT + d] = f ? 1.0f : 0.0f;
            v = f ? 0.0f : v;
        }
        barrier_lds_only();   // ss visible

        // ---- store spikes: 2 rounds of contiguous float4 stores ----
        // (no trailing barrier: next stage overwrites xs, which no wave
        //  reads after the compute barrier; each wave's ss reads drain at
        //  the next barrier's lgkmcnt(0) before ss is rewritten)
#pragma unroll
        for (int p = 0; p < 2; ++p) {
            const f32x4 sv = *(const f32x4*)&ss[p * CTD + tid * 4];
            __builtin_nontemporal_store(sv,
                out4 + (size_t)(r0 + p) * rowq + cq + (size_t)tid);
        }
    }
}

extern "C" void kernel_launch(void* const* d_in, const int* in_sizes, int n_in,
                              void* d_out, int out_size, void* d_ws, size_t ws_size,
                              hipStream_t stream)
{
    const float* x     = (const float*)d_in[0];
    const float* decay = (const float*)d_in[1];
    const float* vth   = (const float*)d_in[2];
    float*       out   = (float*)d_out;

    const int total  = in_sizes[0];                    // B*N*T*D = 67108864
    const int rows   = total / (T_STEPS * D_FEAT);     // B*N = 4096
    const int blocks = rows / 2;                       // 2048
    const int block  = 256;

    plif_fwd_kernel<<<blocks, block, 0, stream>>>(
        (const f32x4*)x, decay, vth, (f32x4*)out);
}